// Round 6
// baseline (420.713 us; speedup 1.0000x reference)
//
#include <hip/hip_runtime.h>

typedef unsigned int u32;
typedef unsigned short u16;
typedef unsigned long long u64;

// Problem constants
#define NPTS 65536
#define PCLD 2048
#define KNN 20
#define HD 128
#define HD2 256
// activations at rest: ROW-MAJOR order-encoded u16: he[row][128] (256 B/row).
// Row-major lets the fused gather read full 256 B neighbor rows from L2.

typedef __attribute__((ext_vector_type(8))) short bf16x8;   // 8 bf16 (4 VGPRs)
typedef __attribute__((ext_vector_type(4))) float f32x4;    // C/D frag
typedef unsigned short us2 __attribute__((ext_vector_type(2)));

__device__ __forceinline__ u16 f2bf(float f) {
    u32 u = __float_as_uint(f);
    u32 r = (u + 0x7FFFu + ((u >> 16) & 1u)) >> 16;  // RNE
    return (u16)r;
}
// order-encode: bf16 bits -> monotone u16 (unsigned compare == float compare)
__device__ __forceinline__ u32 enc2(u32 b) {             // 2 packed values
    u32 s = (b >> 15) & 0x00010001u;
    return b ^ (s * 0x7FFFu) ^ 0x80008000u;
}
__device__ __forceinline__ u32 dec2(u32 e) {
    u32 s = ((~e) >> 15) & 0x00010001u;
    return e ^ (s * 0x7FFFu) ^ 0x80008000u;
}
__device__ __forceinline__ u32 max2(u32 a, u32 b) {      // per-u16 unsigned max
#if __has_builtin(__builtin_elementwise_max)
    us2 x, y; __builtin_memcpy(&x, &a, 4); __builtin_memcpy(&y, &b, 4);
    us2 r = __builtin_elementwise_max(x, y);
    u32 o; __builtin_memcpy(&o, &r, 4); return o;
#else
    u32 lo = ((a & 0xFFFFu) > (b & 0xFFFFu)) ? (a & 0xFFFFu) : (b & 0xFFFFu);
    u32 hi = ((a >> 16) > (b >> 16)) ? (a & 0xFFFF0000u) : (b & 0xFFFF0000u);
    return lo | hi;
#endif
}

// ---------------------------------------------------------------------------
// Weight prep: fp32 -> bf16 + transpose. Blocks 512-767 additionally write
// pts4[i] = (x,y,z,|x|^2) to global for knn's scalar candidate loads.
// ---------------------------------------------------------------------------
__global__ __launch_bounds__(256) void prep_kernel(
    const float* __restrict__ W1_0, const float* __restrict__ W2_0,
    const float* __restrict__ W1_1, const float* __restrict__ W2_1,
    u16* __restrict__ W1_0T, u16* __restrict__ W2_0T,
    u16* __restrict__ W1_1T, u16* __restrict__ W2_1T,
    const float* __restrict__ x, float4* __restrict__ pts4) {
    const int bid = blockIdx.x;
    if (bid < 512) {
        int id = bid * 256 + threadIdx.x;   // 4 * 32768 threads
        int m = id >> 15, e = id & 32767;
        if (m == 0)      { int n = e >> 7, k = e & 127; W1_0T[e] = f2bf(W1_0[k * 256 + n]); }
        else if (m == 1) { int n = e >> 8, k = e & 255; W2_0T[e] = f2bf(W2_0[k * 128 + n]); }
        else if (m == 2) { int n = e >> 7, k = e & 127; W1_1T[e] = f2bf(W1_1[k * 256 + n]); }
        else             { int n = e >> 8, k = e & 255; W2_1T[e] = f2bf(W2_1[k * 128 + n]); }
    } else {
        int i = (bid - 512) * 256 + threadIdx.x;   // 65536 points
        float a = x[3 * i], b = x[3 * i + 1], c = x[3 * i + 2];
        float sq = __fadd_rn(__fadd_rn(__fmul_rn(a, a), __fmul_rn(b, b)), __fmul_rn(c, c));
        pts4[i] = make_float4(a, b, c, sq);
    }
}

// ---------------------------------------------------------------------------
// kNN R14: R2 structure, but the mask pass reads candidates via WAVE-UNIFORM
// global loads (s_load -> SGPR, SMEM pipe, prefetchable) instead of
// ds_read+4x v_readlane. Distance math ops/order identical (same fp32
// results). Pop loop + insertion chain untouched (reads LDS pts[]).
// R10/R12 splits regressed (214/188): occupancy is NOT the lever; the
// readlane dependency chain in the mask pass is the remaining suspect.
// ---------------------------------------------------------------------------
__global__ __launch_bounds__(256) void knn_kernel(const float* __restrict__ x,
                                                  const float4* __restrict__ pts4g,
                                                  u16* __restrict__ nbr) {
    __shared__ float4 pts[PCLD];
    const int cloud = blockIdx.x >> 3;
    const int qi = ((blockIdx.x & 7) << 8) + threadIdx.x;   // local query idx
    const float* xc = x + (u64)cloud * PCLD * 3;
    for (int t = threadIdx.x; t < PCLD; t += 256) {
        float a = xc[3 * t], b = xc[3 * t + 1], c = xc[3 * t + 2];
        float sq = __fadd_rn(__fadd_rn(__fmul_rn(a, a), __fmul_rn(b, b)), __fmul_rn(c, c));
        pts[t] = make_float4(a, b, c, sq);
    }
    __syncthreads();
    const float4 q = pts[qi];
    const float qx = q.x, qy = q.y, qz = q.z, qs = q.w;
    u64 list[KNN];
#pragma unroll
    for (int k = 0; k < KNN; ++k) list[k] = 0xFF800000FFFFFFFFull;  // enc(+inf)
    float thr = __builtin_inff();

    const float4* __restrict__ cnd = pts4g + (u64)cloud * PCLD;  // wave-uniform base
    for (int base = 0; base < PCLD; base += 64) {
        u64 mask = 0;
#pragma unroll
        for (int c = 0; c < 64; ++c) {
            float4 cp = cnd[base + c];   // uniform address -> scalar load
            float dot = __builtin_fmaf(cp.z, qz, __builtin_fmaf(cp.y, qy, __fmul_rn(cp.x, qx)));
            float d = __fsub_rn(__fadd_rn(qs, cp.w), __fmul_rn(2.0f, dot));
            if (d < thr) mask |= (1ull << c);
        }
        while (mask) {
            int c = __builtin_ctzll(mask);
            mask &= mask - 1;
            float4 p2 = pts[base + c];
            float dot = __builtin_fmaf(p2.z, qz, __builtin_fmaf(p2.y, qy, __fmul_rn(p2.x, qx)));
            float d = __fsub_rn(__fadd_rn(qs, p2.w), __fmul_rn(2.0f, dot));
            if (d < thr) {
                u32 ub = __float_as_uint(d);
                u32 e = (ub & 0x80000000u) ? ~ub : (ub | 0x80000000u);
                u64 key = (((u64)e) << 32) | (u32)(base + c);
#pragma unroll
                for (int k = 0; k < KNN; ++k) {
                    u64 lo = key < list[k] ? key : list[k];
                    u64 hi = key < list[k] ? list[k] : key;
                    list[k] = lo; key = hi;
                }
                u32 e19 = (u32)(list[KNN - 1] >> 32);
                u32 ud = (e19 & 0x80000000u) ? (e19 & 0x7FFFFFFFu) : ~e19;
                thr = __uint_as_float(ud);
            }
        }
    }
    u16* out = nbr + (u64)(cloud * PCLD + qi) * KNN;
#pragma unroll
    for (int k = 0; k < KNN; ++k) out[k] = (u16)(u32)list[k];
}

// ---------------------------------------------------------------------------
// Transfer MLP: h0 = encode(bf16(x @ Wt + bt)), ROW-MAJOR he[row][128].
// Consecutive threads cover one row's 256 B -> coalesced uint4 stores.
// ---------------------------------------------------------------------------
__global__ __launch_bounds__(256) void feat_kernel(const float* __restrict__ x,
                                                   const float* __restrict__ Wt,
                                                   const float* __restrict__ bt,
                                                   u16* __restrict__ h0e) {
    int gid = blockIdx.x * 256 + threadIdx.x;   // NPTS*16
    int i = gid >> 4;
    int g = gid & 15;            // 8-channel group within the row
    int c0 = g << 3;
    float x0 = x[3 * i], x1 = x[3 * i + 1], x2 = x[3 * i + 2];
    u32 o[4];
#pragma unroll
    for (int j = 0; j < 8; j += 2) {
        int c = c0 + j;
        float a0 = bt[c]     + x0 * Wt[c]     + x1 * Wt[128 + c]     + x2 * Wt[256 + c];
        float a1 = bt[c + 1] + x0 * Wt[c + 1] + x1 * Wt[128 + c + 1] + x2 * Wt[256 + c + 1];
        o[j >> 1] = enc2(((u32)f2bf(a0)) | (((u32)f2bf(a1)) << 16));
    }
    uint4* dst = (uint4*)&h0e[(u64)i * HD + c0];
    *dst = make_uint4(o[0], o[1], o[2], o[3]);
}

// ---------------------------------------------------------------------------
// Fused GEMM layer — EXACT R3 structure (best: 340.4 total). 64-row tiles,
// 1024 blocks. Phase A gathers own+20 neighbor rows (256 B) from row-major
// he via L2 (R5's 32-row retile was neutral-negative: gather is random-
// access-throughput-bound, not occupancy-bound). XCD swizzle: cloud c ->
// XCD c%8 (each XCD's 4 clouds = 2 MB in its private L2).
// ---------------------------------------------------------------------------
template <int RELU_OUT, int OUT_F32>
__global__ __launch_bounds__(256) void gemm_kernel(
    const u16* __restrict__ he, const u16* __restrict__ nbr_,
    const u16* __restrict__ W1T, const float* __restrict__ b1,
    const u16* __restrict__ W2T, const float* __restrict__ b2,
    const float* __restrict__ g, const float* __restrict__ be,
    const float* __restrict__ rm, const float* __restrict__ rv,
    void* __restrict__ hout_v) {
    __shared__ u16 aggL[64][136];   // +8 pad
    __shared__ u16 hidL[64][264];   // +8 pad
    const int tid = threadIdx.x;
    // XCD-aware swizzle: 1024 blocks = 32 clouds x 32 tiles; b%8 == XCD id.
    const int b = blockIdx.x;
    const int xcd = b & 7, j = b >> 3;           // j in [0,128)
    const int cloud = xcd + 8 * (j >> 5);        // 4 clouds per XCD
    const int tile = j & 31;
    const int R = cloud * PCLD + tile * 64;      // global row base

    // ---- Phase A: fused neighbor-max gather (L2) + decode -> aggL
    {
        const int r = tid >> 2, cg = tid & 3;    // 64 rows x 4 thr (32 ch each)
        const int grow = R + r;
        const u16* __restrict__ hrow = he + (u64)grow * HD + cg * 32;
        uint4 m0 = ((const uint4*)hrow)[0];
        uint4 m1 = ((const uint4*)hrow)[1];
        uint4 m2 = ((const uint4*)hrow)[2];
        uint4 m3 = ((const uint4*)hrow)[3];
        const u64* nb8 = (const u64*)(nbr_ + (u64)grow * KNN);
        u64 nq[5];
#pragma unroll
        for (int w = 0; w < 5; ++w) nq[w] = nb8[w];
        const u16* __restrict__ hcl = he + (u64)cloud * PCLD * HD + cg * 32;
#pragma unroll 4
        for (int t = 0; t < KNN; ++t) {
            int loc = (int)(nq[t >> 2] >> ((t & 3) * 16)) & (PCLD - 1);
            const uint4* vp = (const uint4*)(hcl + (u64)loc * HD);
            uint4 v0 = vp[0], v1 = vp[1], v2 = vp[2], v3 = vp[3];
            m0.x = max2(m0.x, v0.x); m0.y = max2(m0.y, v0.y);
            m0.z = max2(m0.z, v0.z); m0.w = max2(m0.w, v0.w);
            m1.x = max2(m1.x, v1.x); m1.y = max2(m1.y, v1.y);
            m1.z = max2(m1.z, v1.z); m1.w = max2(m1.w, v1.w);
            m2.x = max2(m2.x, v2.x); m2.y = max2(m2.y, v2.y);
            m2.z = max2(m2.z, v2.z); m2.w = max2(m2.w, v2.w);
            m3.x = max2(m3.x, v3.x); m3.y = max2(m3.y, v3.y);
            m3.z = max2(m3.z, v3.z); m3.w = max2(m3.w, v3.w);
        }
        u32* dst = (u32*)&aggL[r][cg * 32];
        dst[0] = dec2(m0.x); dst[1] = dec2(m0.y); dst[2] = dec2(m0.z); dst[3] = dec2(m0.w);
        dst[4] = dec2(m1.x); dst[5] = dec2(m1.y); dst[6] = dec2(m1.z); dst[7] = dec2(m1.w);
        dst[8] = dec2(m2.x); dst[9] = dec2(m2.y); dst[10] = dec2(m2.z); dst[11] = dec2(m2.w);
        dst[12] = dec2(m3.x); dst[13] = dec2(m3.y); dst[14] = dec2(m3.z); dst[15] = dec2(m3.w);
    }
    __syncthreads();

    const int wv = tid >> 6, lane = tid & 63;
    const int lr = lane & 15;
    const int lq = lane >> 4;

    // ---- Phase B: hid = relu(agg @ W1 + b1) -> hidL  (wave owns 64 n-cols)
    {
        f32x4 acc[4][4];
#pragma unroll
        for (int i = 0; i < 4; ++i)
#pragma unroll
            for (int j2 = 0; j2 < 4; ++j2) acc[i][j2] = (f32x4)(0.0f);
        const int nb0 = wv * 64;
#pragma unroll
        for (int ks = 0; ks < 4; ++ks) {
            const int kcol = ks * 32 + lq * 8;
            bf16x8 af[4], bfr[4];
#pragma unroll
            for (int mt = 0; mt < 4; ++mt)
                af[mt] = *(const bf16x8*)&aggL[mt * 16 + lr][kcol];
#pragma unroll
            for (int nt = 0; nt < 4; ++nt)
                bfr[nt] = *(const bf16x8*)&W1T[(u64)(nb0 + nt * 16 + lr) * HD + kcol];
#pragma unroll
            for (int mt = 0; mt < 4; ++mt)
#pragma unroll
                for (int nt = 0; nt < 4; ++nt)
                    acc[mt][nt] = __builtin_amdgcn_mfma_f32_16x16x32_bf16(af[mt], bfr[nt], acc[mt][nt], 0, 0, 0);
        }
#pragma unroll
        for (int nt = 0; nt < 4; ++nt) {
            const int c = nb0 + nt * 16 + lr;
            const float bias = b1[c];
#pragma unroll
            for (int mt = 0; mt < 4; ++mt)
#pragma unroll
                for (int r2 = 0; r2 < 4; ++r2) {
                    float v = fmaxf(acc[mt][nt][r2] + bias, 0.0f);
                    hidL[mt * 16 + lq * 4 + r2][c] = f2bf(v);
                }
        }
    }
    __syncthreads();

    // ---- Phase C: out = BN(hid @ W2 + b2) (+ReLU) -> global
    {
        f32x4 acc[4][2];
#pragma unroll
        for (int i = 0; i < 4; ++i) { acc[i][0] = (f32x4)(0.0f); acc[i][1] = (f32x4)(0.0f); }
        const int nb0 = wv * 32;
#pragma unroll
        for (int ks = 0; ks < 8; ++ks) {
            const int kcol = ks * 32 + lq * 8;
            bf16x8 af[4], bfr[2];
#pragma unroll
            for (int mt = 0; mt < 4; ++mt)
                af[mt] = *(const bf16x8*)&hidL[mt * 16 + lr][kcol];
#pragma unroll
            for (int nt = 0; nt < 2; ++nt)
                bfr[nt] = *(const bf16x8*)&W2T[(u64)(nb0 + nt * 16 + lr) * HD2 + kcol];
#pragma unroll
            for (int mt = 0; mt < 4; ++mt)
#pragma unroll
                for (int nt = 0; nt < 2; ++nt)
                    acc[mt][nt] = __builtin_amdgcn_mfma_f32_16x16x32_bf16(af[mt], bfr[nt], acc[mt][nt], 0, 0, 0);
        }
#pragma unroll
        for (int nt = 0; nt < 2; ++nt) {
            const int c = nb0 + nt * 16 + lr;
            const float bias = b2[c];
            const float sc = g[c] * (1.0f / sqrtf(rv[c] + 1e-5f));
            const float rmc = rm[c];
            const float bec = be[c];
#pragma unroll
            for (int mt = 0; mt < 4; ++mt)
#pragma unroll
                for (int r2 = 0; r2 < 4; ++r2) {
                    float v = acc[mt][nt][r2] + bias;
                    v = (v - rmc) * sc + bec;
                    if (RELU_OUT) v = fmaxf(v, 0.0f);
                    const int row = R + mt * 16 + lq * 4 + r2;
                    if (OUT_F32) {
                        ((float*)hout_v)[(u64)row * HD + c] = v;
                    } else {
                        u16 bb = f2bf(v);
                        u16 e = bb ^ ((bb & 0x8000u) ? (u16)0xFFFFu : (u16)0x8000u);
                        ((u16*)hout_v)[(u64)row * HD + c] = e;   // row-major encoded
                    }
                }
        }
    }
}

// ---------------------------------------------------------------------------
extern "C" void kernel_launch(void* const* d_in, const int* in_sizes, int n_in,
                              void* d_out, int out_size, void* d_ws, size_t ws_size,
                              hipStream_t stream) {
    const float* x    = (const float*)d_in[0];
    const float* Wt   = (const float*)d_in[2];
    const float* bt   = (const float*)d_in[3];
    const float* W1_0 = (const float*)d_in[4];
    const float* b1_0 = (const float*)d_in[5];
    const float* W2_0 = (const float*)d_in[6];
    const float* b2_0 = (const float*)d_in[7];
    const float* g0   = (const float*)d_in[8];
    const float* be0  = (const float*)d_in[9];
    const float* rm0  = (const float*)d_in[10];
    const float* rv0  = (const float*)d_in[11];
    const float* W1_1 = (const float*)d_in[12];
    const float* b1_1 = (const float*)d_in[13];
    const float* W2_1 = (const float*)d_in[14];
    const float* b2_1 = (const float*)d_in[15];
    const float* g1   = (const float*)d_in[16];
    const float* be1  = (const float*)d_in[17];
    const float* rm1  = (const float*)d_in[18];
    const float* rv1  = (const float*)d_in[19];

    char* ws = (char*)d_ws;
    u16* he0  = (u16*)ws;                                   // 16 MB layer-0 acts
    u16* he1  = (u16*)(ws + 16777216);                      // 16 MB layer-1 acts
    float4* pts4 = (float4*)(ws + 16777216);                // 1 MB, aliases he1
    // (pts4 used only by prep+knn, both complete before gemm0 writes he1)
    u16* W10T = (u16*)(ws + 2 * 16777216);                  // 64 KB each
    u16* W20T = W10T + 32768;
    u16* W11T = W20T + 32768;
    u16* W21T = W11T + 32768;
    u16* nbr  = (u16*)(ws + 2 * 16777216 + 4 * 65536);      // 2.62 MB
    // total ws ~35.2 MB

    prep_kernel<<<768, 256, 0, stream>>>(W1_0, W2_0, W1_1, W2_1, W10T, W20T, W11T, W21T,
                                         x, pts4);
    knn_kernel<<<256, 256, 0, stream>>>(x, pts4, nbr);
    feat_kernel<<<4096, 256, 0, stream>>>(x, Wt, bt, he0);
    // layer 0: fused gather+GEMM, he0 -> he1
    gemm_kernel<1, 0><<<1024, 256, 0, stream>>>(he0, nbr, W10T, b1_0, W20T, b2_0,
                                                g0, be0, rm0, rv0, he1);
    // layer 1: fused gather+GEMM, he1 -> d_out (fp32)
    gemm_kernel<0, 1><<<1024, 256, 0, stream>>>(he1, nbr, W11T, b1_1, W21T, b2_1,
                                                g1, be1, rm1, rv1, d_out);
}

// Round 7
// 322.505 us; speedup vs baseline: 1.3045x; 1.3045x over previous
//
#include <hip/hip_runtime.h>

typedef unsigned int u32;
typedef unsigned short u16;
typedef unsigned long long u64;

// Problem constants
#define NPTS 65536
#define PCLD 2048
#define KNN 20
#define HD 128
#define HD2 256
// activations at rest: ROW-MAJOR order-encoded u16: he[row][128] (256 B/row).
// Row-major lets the fused gather read full 256 B neighbor rows from L2.

typedef __attribute__((ext_vector_type(8))) short bf16x8;   // 8 bf16 (4 VGPRs)
typedef __attribute__((ext_vector_type(4))) float f32x4;    // C/D frag
typedef unsigned short us2 __attribute__((ext_vector_type(2)));

__device__ __forceinline__ u16 f2bf(float f) {
    u32 u = __float_as_uint(f);
    u32 r = (u + 0x7FFFu + ((u >> 16) & 1u)) >> 16;  // RNE
    return (u16)r;
}
// order-encode: bf16 bits -> monotone u16 (unsigned compare == float compare)
__device__ __forceinline__ u32 enc2(u32 b) {             // 2 packed values
    u32 s = (b >> 15) & 0x00010001u;
    return b ^ (s * 0x7FFFu) ^ 0x80008000u;
}
__device__ __forceinline__ u32 dec2(u32 e) {
    u32 s = ((~e) >> 15) & 0x00010001u;
    return e ^ (s * 0x7FFFu) ^ 0x80008000u;
}
__device__ __forceinline__ u32 max2(u32 a, u32 b) {      // per-u16 unsigned max
#if __has_builtin(__builtin_elementwise_max)
    us2 x, y; __builtin_memcpy(&x, &a, 4); __builtin_memcpy(&y, &b, 4);
    us2 r = __builtin_elementwise_max(x, y);
    u32 o; __builtin_memcpy(&o, &r, 4); return o;
#else
    u32 lo = ((a & 0xFFFFu) > (b & 0xFFFFu)) ? (a & 0xFFFFu) : (b & 0xFFFFu);
    u32 hi = ((a >> 16) > (b >> 16)) ? (a & 0xFFFF0000u) : (b & 0xFFFF0000u);
    return lo | hi;
#endif
}

// ---------------------------------------------------------------------------
// Weight prep: fp32 -> bf16 + transpose (exact R3 version).
// ---------------------------------------------------------------------------
__global__ __launch_bounds__(256) void prep_kernel(
    const float* __restrict__ W1_0, const float* __restrict__ W2_0,
    const float* __restrict__ W1_1, const float* __restrict__ W2_1,
    u16* __restrict__ W1_0T, u16* __restrict__ W2_0T,
    u16* __restrict__ W1_1T, u16* __restrict__ W2_1T) {
    int id = blockIdx.x * 256 + threadIdx.x;   // 4 * 32768 threads
    int m = id >> 15, e = id & 32767;
    if (m == 0)      { int n = e >> 7, k = e & 127; W1_0T[e] = f2bf(W1_0[k * 256 + n]); }
    else if (m == 1) { int n = e >> 8, k = e & 255; W2_0T[e] = f2bf(W2_0[k * 128 + n]); }
    else if (m == 2) { int n = e >> 7, k = e & 127; W1_1T[e] = f2bf(W1_1[k * 256 + n]); }
    else             { int n = e >> 8, k = e & 255; W2_1T[e] = f2bf(W2_1[k * 128 + n]); }
}

// ---------------------------------------------------------------------------
// kNN — EXACT R2 structure (empirical best: 155-164 us; PERMANENTLY FROZEN).
// Failed attacks: R10 candidate-split (214, insertion inflation); R12
// shared-thr split (188, split machinery > latency gain); R14 scalar
// candidate loads (237, SMEM-latency-bound, VALUBusy 63->36, FETCH 3.6x).
// readlane broadcast from LDS is the verified optimum for this kernel.
// ---------------------------------------------------------------------------
__global__ __launch_bounds__(256) void knn_kernel(const float* __restrict__ x,
                                                  u16* __restrict__ nbr) {
    __shared__ float4 pts[PCLD];
    const int cloud = blockIdx.x >> 3;
    const int qi = ((blockIdx.x & 7) << 8) + threadIdx.x;   // local query idx
    const float* xc = x + (u64)cloud * PCLD * 3;
    for (int t = threadIdx.x; t < PCLD; t += 256) {
        float a = xc[3 * t], b = xc[3 * t + 1], c = xc[3 * t + 2];
        float sq = __fadd_rn(__fadd_rn(__fmul_rn(a, a), __fmul_rn(b, b)), __fmul_rn(c, c));
        pts[t] = make_float4(a, b, c, sq);
    }
    __syncthreads();
    const float4 q = pts[qi];
    const float qx = q.x, qy = q.y, qz = q.z, qs = q.w;
    const int lane = threadIdx.x & 63;
    u64 list[KNN];
#pragma unroll
    for (int k = 0; k < KNN; ++k) list[k] = 0xFF800000FFFFFFFFull;  // enc(+inf)
    float thr = __builtin_inff();

    for (int base = 0; base < PCLD; base += 64) {
        float4 cp = pts[base + lane];   // 1 ds_read_b128 per 64 candidates
        u64 mask = 0;
#pragma unroll
        for (int c = 0; c < 64; ++c) {
            float cx = __uint_as_float(__builtin_amdgcn_readlane(__float_as_uint(cp.x), c));
            float cy = __uint_as_float(__builtin_amdgcn_readlane(__float_as_uint(cp.y), c));
            float cz = __uint_as_float(__builtin_amdgcn_readlane(__float_as_uint(cp.z), c));
            float cs = __uint_as_float(__builtin_amdgcn_readlane(__float_as_uint(cp.w), c));
            float dot = __builtin_fmaf(cz, qz, __builtin_fmaf(cy, qy, __fmul_rn(cx, qx)));
            float d = __fsub_rn(__fadd_rn(qs, cs), __fmul_rn(2.0f, dot));
            if (d < thr) mask |= (1ull << c);
        }
        while (mask) {
            int c = __builtin_ctzll(mask);
            mask &= mask - 1;
            float4 p2 = pts[base + c];
            float dot = __builtin_fmaf(p2.z, qz, __builtin_fmaf(p2.y, qy, __fmul_rn(p2.x, qx)));
            float d = __fsub_rn(__fadd_rn(qs, p2.w), __fmul_rn(2.0f, dot));
            if (d < thr) {
                u32 ub = __float_as_uint(d);
                u32 e = (ub & 0x80000000u) ? ~ub : (ub | 0x80000000u);
                u64 key = (((u64)e) << 32) | (u32)(base + c);
#pragma unroll
                for (int k = 0; k < KNN; ++k) {
                    u64 lo = key < list[k] ? key : list[k];
                    u64 hi = key < list[k] ? list[k] : key;
                    list[k] = lo; key = hi;
                }
                u32 e19 = (u32)(list[KNN - 1] >> 32);
                u32 ud = (e19 & 0x80000000u) ? (e19 & 0x7FFFFFFFu) : ~e19;
                thr = __uint_as_float(ud);
            }
        }
    }
    u16* out = nbr + (u64)(cloud * PCLD + qi) * KNN;
#pragma unroll
    for (int k = 0; k < KNN; ++k) out[k] = (u16)(u32)list[k];
}

// ---------------------------------------------------------------------------
// Transfer MLP: h0 = encode(bf16(x @ Wt + bt)), ROW-MAJOR he[row][128].
// Consecutive threads cover one row's 256 B -> coalesced uint4 stores.
// ---------------------------------------------------------------------------
__global__ __launch_bounds__(256) void feat_kernel(const float* __restrict__ x,
                                                   const float* __restrict__ Wt,
                                                   const float* __restrict__ bt,
                                                   u16* __restrict__ h0e) {
    int gid = blockIdx.x * 256 + threadIdx.x;   // NPTS*16
    int i = gid >> 4;
    int g = gid & 15;            // 8-channel group within the row
    int c0 = g << 3;
    float x0 = x[3 * i], x1 = x[3 * i + 1], x2 = x[3 * i + 2];
    u32 o[4];
#pragma unroll
    for (int j = 0; j < 8; j += 2) {
        int c = c0 + j;
        float a0 = bt[c]     + x0 * Wt[c]     + x1 * Wt[128 + c]     + x2 * Wt[256 + c];
        float a1 = bt[c + 1] + x0 * Wt[c + 1] + x1 * Wt[128 + c + 1] + x2 * Wt[256 + c + 1];
        o[j >> 1] = enc2(((u32)f2bf(a0)) | (((u32)f2bf(a1)) << 16));
    }
    uint4* dst = (uint4*)&h0e[(u64)i * HD + c0];
    *dst = make_uint4(o[0], o[1], o[2], o[3]);
}

// ---------------------------------------------------------------------------
// Fused GEMM layer — R3 structure with COALESCED Phase-A gather.
// Old mapping: thread cg owned contiguous bytes [cg*64, cg*64+64) of a row
// -> per VMEM instruction the 64 lanes hit 64 distinct 64-B segments
// (16 rows x 4 chunks) -> 64 L1 lookups/instr -> ~36 us/layer (L1-lookup
// bound; matches measurement). New mapping: thread cg reads the cg-th 16-B
// quarter of EACH 64-B segment (offsets {0,64,128,192}+cg*16) -> the 4
// cg-lanes of a row coalesce into ONE segment -> 16 lookups/instr (4x).
// Pure index permutation: same data, same channel positions per thread,
// bit-identical result. Phases B/C unchanged from R3.
// ---------------------------------------------------------------------------
template <int RELU_OUT, int OUT_F32>
__global__ __launch_bounds__(256) void gemm_kernel(
    const u16* __restrict__ he, const u16* __restrict__ nbr_,
    const u16* __restrict__ W1T, const float* __restrict__ b1,
    const u16* __restrict__ W2T, const float* __restrict__ b2,
    const float* __restrict__ g, const float* __restrict__ be,
    const float* __restrict__ rm, const float* __restrict__ rv,
    void* __restrict__ hout_v) {
    __shared__ u16 aggL[64][136];   // +8 pad (272 B row stride = 17x16 B, aligned)
    __shared__ u16 hidL[64][264];   // +8 pad
    const int tid = threadIdx.x;
    // XCD-aware swizzle: 1024 blocks = 32 clouds x 32 tiles; b%8 == XCD id.
    const int b = blockIdx.x;
    const int xcd = b & 7, j = b >> 3;           // j in [0,128)
    const int cloud = xcd + 8 * (j >> 5);        // 4 clouds per XCD
    const int tile = j & 31;
    const int R = cloud * PCLD + tile * 64;      // global row base

    // ---- Phase A: fused neighbor-max gather (L2) + decode -> aggL
    {
        const int r = tid >> 2, cg = tid & 3;    // 64 rows x 4 thr
        const int co = cg * 8;                   // u16 offset of this thread's 16-B quarter
        const int grow = R + r;
        const u16* __restrict__ hrow = he + (u64)grow * HD;
        uint4 m0 = *(const uint4*)&hrow[co];
        uint4 m1 = *(const uint4*)&hrow[32 + co];
        uint4 m2 = *(const uint4*)&hrow[64 + co];
        uint4 m3 = *(const uint4*)&hrow[96 + co];
        const u64* nb8 = (const u64*)(nbr_ + (u64)grow * KNN);
        u64 nq[5];
#pragma unroll
        for (int w = 0; w < 5; ++w) nq[w] = nb8[w];
        const u16* __restrict__ hcl = he + (u64)cloud * PCLD * HD;
#pragma unroll 4
        for (int t = 0; t < KNN; ++t) {
            int loc = (int)(nq[t >> 2] >> ((t & 3) * 16)) & (PCLD - 1);
            const u16* __restrict__ vrow = hcl + (u64)loc * HD;
            uint4 v0 = *(const uint4*)&vrow[co];
            uint4 v1 = *(const uint4*)&vrow[32 + co];
            uint4 v2 = *(const uint4*)&vrow[64 + co];
            uint4 v3 = *(const uint4*)&vrow[96 + co];
            m0.x = max2(m0.x, v0.x); m0.y = max2(m0.y, v0.y);
            m0.z = max2(m0.z, v0.z); m0.w = max2(m0.w, v0.w);
            m1.x = max2(m1.x, v1.x); m1.y = max2(m1.y, v1.y);
            m1.z = max2(m1.z, v1.z); m1.w = max2(m1.w, v1.w);
            m2.x = max2(m2.x, v2.x); m2.y = max2(m2.y, v2.y);
            m2.z = max2(m2.z, v2.z); m2.w = max2(m2.w, v2.w);
            m3.x = max2(m3.x, v3.x); m3.y = max2(m3.y, v3.y);
            m3.z = max2(m3.z, v3.z); m3.w = max2(m3.w, v3.w);
        }
        *(uint4*)&aggL[r][co]      = make_uint4(dec2(m0.x), dec2(m0.y), dec2(m0.z), dec2(m0.w));
        *(uint4*)&aggL[r][32 + co] = make_uint4(dec2(m1.x), dec2(m1.y), dec2(m1.z), dec2(m1.w));
        *(uint4*)&aggL[r][64 + co] = make_uint4(dec2(m2.x), dec2(m2.y), dec2(m2.z), dec2(m2.w));
        *(uint4*)&aggL[r][96 + co] = make_uint4(dec2(m3.x), dec2(m3.y), dec2(m3.z), dec2(m3.w));
    }
    __syncthreads();

    const int wv = tid >> 6, lane = tid & 63;
    const int lr = lane & 15;
    const int lq = lane >> 4;

    // ---- Phase B: hid = relu(agg @ W1 + b1) -> hidL  (wave owns 64 n-cols)
    {
        f32x4 acc[4][4];
#pragma unroll
        for (int i = 0; i < 4; ++i)
#pragma unroll
            for (int j2 = 0; j2 < 4; ++j2) acc[i][j2] = (f32x4)(0.0f);
        const int nb0 = wv * 64;
#pragma unroll
        for (int ks = 0; ks < 4; ++ks) {
            const int kcol = ks * 32 + lq * 8;
            bf16x8 af[4], bfr[4];
#pragma unroll
            for (int mt = 0; mt < 4; ++mt)
                af[mt] = *(const bf16x8*)&aggL[mt * 16 + lr][kcol];
#pragma unroll
            for (int nt = 0; nt < 4; ++nt)
                bfr[nt] = *(const bf16x8*)&W1T[(u64)(nb0 + nt * 16 + lr) * HD + kcol];
#pragma unroll
            for (int mt = 0; mt < 4; ++mt)
#pragma unroll
                for (int nt = 0; nt < 4; ++nt)
                    acc[mt][nt] = __builtin_amdgcn_mfma_f32_16x16x32_bf16(af[mt], bfr[nt], acc[mt][nt], 0, 0, 0);
        }
#pragma unroll
        for (int nt = 0; nt < 4; ++nt) {
            const int c = nb0 + nt * 16 + lr;
            const float bias = b1[c];
#pragma unroll
            for (int mt = 0; mt < 4; ++mt)
#pragma unroll
                for (int r2 = 0; r2 < 4; ++r2) {
                    float v = fmaxf(acc[mt][nt][r2] + bias, 0.0f);
                    hidL[mt * 16 + lq * 4 + r2][c] = f2bf(v);
                }
        }
    }
    __syncthreads();

    // ---- Phase C: out = BN(hid @ W2 + b2) (+ReLU) -> global
    {
        f32x4 acc[4][2];
#pragma unroll
        for (int i = 0; i < 4; ++i) { acc[i][0] = (f32x4)(0.0f); acc[i][1] = (f32x4)(0.0f); }
        const int nb0 = wv * 32;
#pragma unroll
        for (int ks = 0; ks < 8; ++ks) {
            const int kcol = ks * 32 + lq * 8;
            bf16x8 af[4], bfr[2];
#pragma unroll
            for (int mt = 0; mt < 4; ++mt)
                af[mt] = *(const bf16x8*)&hidL[mt * 16 + lr][kcol];
#pragma unroll
            for (int nt = 0; nt < 2; ++nt)
                bfr[nt] = *(const bf16x8*)&W2T[(u64)(nb0 + nt * 16 + lr) * HD2 + kcol];
#pragma unroll
            for (int mt = 0; mt < 4; ++mt)
#pragma unroll
                for (int nt = 0; nt < 2; ++nt)
                    acc[mt][nt] = __builtin_amdgcn_mfma_f32_16x16x32_bf16(af[mt], bfr[nt], acc[mt][nt], 0, 0, 0);
        }
#pragma unroll
        for (int nt = 0; nt < 2; ++nt) {
            const int c = nb0 + nt * 16 + lr;
            const float bias = b2[c];
            const float sc = g[c] * (1.0f / sqrtf(rv[c] + 1e-5f));
            const float rmc = rm[c];
            const float bec = be[c];
#pragma unroll
            for (int mt = 0; mt < 4; ++mt)
#pragma unroll
                for (int r2 = 0; r2 < 4; ++r2) {
                    float v = acc[mt][nt][r2] + bias;
                    v = (v - rmc) * sc + bec;
                    if (RELU_OUT) v = fmaxf(v, 0.0f);
                    const int row = R + mt * 16 + lq * 4 + r2;
                    if (OUT_F32) {
                        ((float*)hout_v)[(u64)row * HD + c] = v;
                    } else {
                        u16 bb = f2bf(v);
                        u16 e = bb ^ ((bb & 0x8000u) ? (u16)0xFFFFu : (u16)0x8000u);
                        ((u16*)hout_v)[(u64)row * HD + c] = e;   // row-major encoded
                    }
                }
        }
    }
}

// ---------------------------------------------------------------------------
extern "C" void kernel_launch(void* const* d_in, const int* in_sizes, int n_in,
                              void* d_out, int out_size, void* d_ws, size_t ws_size,
                              hipStream_t stream) {
    const float* x    = (const float*)d_in[0];
    const float* Wt   = (const float*)d_in[2];
    const float* bt   = (const float*)d_in[3];
    const float* W1_0 = (const float*)d_in[4];
    const float* b1_0 = (const float*)d_in[5];
    const float* W2_0 = (const float*)d_in[6];
    const float* b2_0 = (const float*)d_in[7];
    const float* g0   = (const float*)d_in[8];
    const float* be0  = (const float*)d_in[9];
    const float* rm0  = (const float*)d_in[10];
    const float* rv0  = (const float*)d_in[11];
    const float* W1_1 = (const float*)d_in[12];
    const float* b1_1 = (const float*)d_in[13];
    const float* W2_1 = (const float*)d_in[14];
    const float* b2_1 = (const float*)d_in[15];
    const float* g1   = (const float*)d_in[16];
    const float* be1  = (const float*)d_in[17];
    const float* rm1  = (const float*)d_in[18];
    const float* rv1  = (const float*)d_in[19];

    char* ws = (char*)d_ws;
    u16* he0  = (u16*)ws;                                   // 16 MB layer-0 acts
    u16* he1  = (u16*)(ws + 16777216);                      // 16 MB layer-1 acts
    u16* W10T = (u16*)(ws + 2 * 16777216);                  // 64 KB each
    u16* W20T = W10T + 32768;
    u16* W11T = W20T + 32768;
    u16* W21T = W11T + 32768;
    u16* nbr  = (u16*)(ws + 2 * 16777216 + 4 * 65536);      // 2.62 MB
    // total ws ~35.2 MB

    knn_kernel<<<256, 256, 0, stream>>>(x, nbr);
    prep_kernel<<<512, 256, 0, stream>>>(W1_0, W2_0, W1_1, W2_1, W10T, W20T, W11T, W21T);
    feat_kernel<<<4096, 256, 0, stream>>>(x, Wt, bt, he0);
    // layer 0: fused gather+GEMM, he0 -> he1
    gemm_kernel<1, 0><<<1024, 256, 0, stream>>>(he0, nbr, W10T, b1_0, W20T, b2_0,
                                                g0, be0, rm0, rv0, he1);
    // layer 1: fused gather+GEMM, he1 -> d_out (fp32)
    gemm_kernel<0, 1><<<1024, 256, 0, stream>>>(he1, nbr, W11T, b1_1, W21T, b2_1,
                                                g1, be1, rm1, rv1, d_out);
}